// Round 18
// baseline (930.510 us; speedup 1.0000x reference)
//
#include <hip/hip_runtime.h>

#define NN 50000
#define NE 1600000
#define NG 64
#define HD 64
#define BN_EPS 1e-5f
#define NTILES ((NN + 31) / 32)
#define NBUCK 8
#define NPB 6250                 // NN / NBUCK exactly
#define NBINS (NBUCK * NN)       // 400000
#define NEP (NE + 2048)          // padded edge array length (8 buckets x 127 max)
#define SLOTS 1792               // per-XCD 128-edge chunk slots for edge pass
#define CHUNK 2000               // bins per scan chunk (NN % CHUNK == 0)
#define NCHUNK (NBINS / CHUNK)   // 200
#define CPB (NCHUNK / NBUCK)     // 25 chunks per bucket

typedef unsigned short ushort_t;
typedef unsigned int uint_t;
typedef __attribute__((ext_vector_type(8))) short bf16x8;
typedef __attribute__((ext_vector_type(4))) float f32x4;

__device__ __forceinline__ float b2f(ushort_t u) {
  union { uint_t i; float f; } v; v.i = ((uint_t)u) << 16; return v.f;
}
__device__ __forceinline__ ushort_t f2b(float f) {
  union { float f; uint_t i; } v; v.f = f;
  uint_t x = v.i;
  return (ushort_t)((x + 0x7fffu + ((x >> 16) & 1u)) >> 16);
}
// pack f32 into (bf16_hi | bf16_lo<<16); hi+lo reconstructs f to ~2^-17 rel
__device__ __forceinline__ uint_t packsplit(float f) {
  ushort_t hi = f2b(f);
  float r = f - b2f(hi);
  ushort_t lo = f2b(r);
  return (uint_t)hi | ((uint_t)lo << 16);
}
__device__ __forceinline__ float LDF(const void* p, int i, int isb) {
  return isb ? b2f(((const ushort_t*)p)[i]) : ((const float*)p)[i];
}
__device__ __forceinline__ int LDI(const void* p, int i, int is64) {
  return is64 ? ((const int*)p)[2 * i] : ((const int*)p)[i];
}
__device__ __forceinline__ int clampi(int v, int hi) {
  return (v < 0) ? 0 : (v >= hi ? hi - 1 : v);
}

// Sniff dtypes from bit patterns (bf16 exp-byte clustering; int64 high words zero).
__global__ void detect_k(const uint_t* __restrict__ xw, const uint_t* __restrict__ ew,
                         int* __restrict__ flags) {
  int t = threadIdx.x;  // 64 threads
  uint_t w = xw[t];
  uint_t b = (w >> 8) & 0x7fu;
  unsigned long long m1 = __ballot(b >= 0x3au && b <= 0x42u);
  unsigned long long m2 = __ballot(ew[2 * t + 1] == 0u);
  if (t == 0) {
    flags[0] = (__popcll(m1) >= 32) ? 1 : 0;
    flags[1] = (__popcll(m2) >= 56) ? 1 : 0;
  }
}

__global__ void __launch_bounds__(256) node_embed(
    const void* __restrict__ x, const void* __restrict__ W,
    const void* __restrict__ b, float* __restrict__ h, const int* __restrict__ flags) {
  __shared__ float xs[64 * 32];
  int isb = flags[0];
  int t = threadIdx.x;
  int base = blockIdx.x * 64;
  int nodes = NN - base; if (nodes > 64) nodes = 64;
  int idx = t * 8;
  if (idx < nodes * 32) {
    if (isb) {
      const uint4* p = (const uint4*)((const ushort_t*)x + base * 32);
      uint4 u = p[t];
      ushort_t* pu = (ushort_t*)&u;
      #pragma unroll
      for (int q = 0; q < 8; q++) xs[idx + q] = b2f(pu[q]);
    } else {
      const float4* p = (const float4*)((const float*)x + base * 32);
      float4 a = p[2 * t], d = p[2 * t + 1];
      xs[idx + 0] = a.x; xs[idx + 1] = a.y; xs[idx + 2] = a.z; xs[idx + 3] = a.w;
      xs[idx + 4] = d.x; xs[idx + 5] = d.y; xs[idx + 6] = d.z; xs[idx + 7] = d.w;
    }
  }
  int c = t & 63, s0 = t >> 6;
  float w[32];
  #pragma unroll
  for (int k = 0; k < 32; k++) w[k] = LDF(W, k * 64 + c, isb);
  float bc = LDF(b, c, isb);
  __syncthreads();
  #pragma unroll 4
  for (int i = 0; i < 16; i++) {
    int slot = s0 * 16 + i;
    int node = base + slot;
    if (node < NN) {
      float acc = bc;
      #pragma unroll
      for (int k = 0; k < 32; k++) acc += xs[slot * 32 + k] * w[k];
      h[node * 64 + c] = acc;
    }
  }
}

// ---------- counting sort of edges by (src-bucket, dst) (once per call) ------
__global__ void __launch_bounds__(256) hist_k(
    const void* __restrict__ eidx, int* __restrict__ hist, const int* __restrict__ flags) {
  int is64 = flags[1];
  int e = blockIdx.x * 256 + threadIdx.x;
  if (e >= NE) return;
  int d = clampi(LDI(eidx, NE + e, is64), NN);
  int s = clampi(LDI(eidx, e, is64), NN);
  int bin = (s / NPB) * NN + d;
  atomicAdd(&hist[bin], 1);
}

// ---- hierarchical scan over 400k bins ----
// scan_a: per-chunk sums (200 blocks x 2000 bins).
__global__ void __launch_bounds__(256) scan_a(
    const int* __restrict__ hist, int* __restrict__ csum) {
  __shared__ int red[256];
  int c = blockIdx.x, t = threadIdx.x;
  int s = 0;
  if (t < 250) {
    const int4* h4 = (const int4*)(hist + c * CHUNK) + t * 2;
    int4 a = h4[0], b = h4[1];
    s = a.x + a.y + a.z + a.w + b.x + b.y + b.z + b.w;
  }
  red[t] = s;
  __syncthreads();
  for (int d = 128; d > 0; d >>= 1) {
    if (t < d) red[t] += red[t + d];
    __syncthreads();
  }
  if (t == 0) csum[c] = red[0];
}

// scan_b: bucket totals + 128-aligned starts A[b] + per-chunk bases.
// meta[0..8] = aligned bucket starts (meta[8] = padded total);
// meta[16+b] = real end of bucket b.
__global__ void __launch_bounds__(256) scan_b(
    const int* __restrict__ csum, int* __restrict__ cbase, int* __restrict__ meta) {
  __shared__ int sc[NCHUNK];
  __shared__ int sT[NBUCK];
  __shared__ int sA[NBUCK + 1];
  int t = threadIdx.x;
  if (t < NCHUNK) sc[t] = csum[t];
  __syncthreads();
  if (t < NBUCK) {
    int T = 0;
    for (int i = 0; i < CPB; i++) T += sc[t * CPB + i];
    sT[t] = T;
  }
  __syncthreads();
  if (t == 0) {
    int a = 0;
    for (int b = 0; b < NBUCK; b++) {
      sA[b] = a;
      meta[b] = a;
      meta[16 + b] = a + sT[b];
      a = (a + sT[b] + 127) & ~127;   // 128-edge chunk alignment
    }
    meta[NBUCK] = a;
    sA[NBUCK] = a;
  }
  __syncthreads();
  if (t < NBUCK) {
    int run = sA[t];
    for (int i = 0; i < CPB; i++) { cbase[t * CPB + i] = run; run += sc[t * CPB + i]; }
  }
}

// scan_c: per-chunk exclusive scan, seeded by cbase (200 blocks).
__global__ void __launch_bounds__(256) scan_c(
    const int* __restrict__ hist, const int* __restrict__ cbase,
    int* __restrict__ starts) {
  __shared__ int buf[256];
  int c = blockIdx.x, t = threadIdx.x;
  int4 a = {0, 0, 0, 0}, b = {0, 0, 0, 0};
  int s = 0;
  if (t < 250) {
    const int4* h4 = (const int4*)(hist + c * CHUNK) + t * 2;
    a = h4[0]; b = h4[1];
    s = a.x + a.y + a.z + a.w + b.x + b.y + b.z + b.w;
  }
  buf[t] = s;
  __syncthreads();
  for (int d = 1; d < 256; d <<= 1) {
    int x = (t >= d) ? buf[t - d] : 0;
    __syncthreads();
    buf[t] += x;
    __syncthreads();
  }
  if (t < 250) {
    int run = cbase[c] + buf[t] - s;  // exclusive prefix for this thread's 8 bins
    int4 o1, o2;
    o1.x = run; run += a.x;
    o1.y = run; run += a.y;
    o1.z = run; run += a.z;
    o1.w = run; run += a.w;
    o2.x = run; run += b.x;
    o2.y = run; run += b.y;
    o2.z = run; run += b.z;
    o2.w = run; run += b.w;
    int4* s4 = (int4*)(starts + c * CHUNK) + t * 2;
    s4[0] = o1; s4[1] = o2;
  }
}

// fill pad slots (between real end and aligned end of each bucket)
__global__ void pad_fill(const int* __restrict__ meta, int* __restrict__ perm,
                         uint2* __restrict__ sdp) {
  int t = threadIdx.x;  // 64
  for (int b = 0; b < NBUCK; b++) {
    int re = meta[16 + b], ae = meta[b + 1];
    for (int p = re + t; p < ae; p += 64) {
      perm[p] = 0;
      sdp[p] = make_uint2(0u, (uint_t)NN);
    }
  }
}

// 2 independent stores/edge (R9=3 stores/208MB/104us; R10=1 dep store/101MB/
// 140us -> middle point: ~2/3 the dirty lines, 2 independent store chains).
__global__ void __launch_bounds__(256) scatter_k(
    const void* __restrict__ eidx, int* __restrict__ cursor,
    int* __restrict__ perm, uint2* __restrict__ sdp,
    const int* __restrict__ flags) {
  int is64 = flags[1];
  int e = blockIdx.x * 256 + threadIdx.x;
  if (e >= NE) return;
  int d = clampi(LDI(eidx, NE + e, is64), NN);
  int s = clampi(LDI(eidx, e, is64), NN);
  int bin = (s / NPB) * NN + d;
  int pos = atomicAdd(&cursor[bin], 1);
  perm[pos] = e;
  sdp[pos] = make_uint2((uint_t)s, (uint_t)d);
}

// ---- one-time: gather eattr by perm into sorted order, pre-laid-out as
// MFMA A-fragments (bf16 hi + lo split). Per 16-edge tile: 512B hi (+512B lo).
__global__ void __launch_bounds__(256) pack_eattr(
    const void* __restrict__ eattr, const int* __restrict__ perm,
    ushort_t* __restrict__ phi, ushort_t* __restrict__ plo,
    const int* __restrict__ flags, const int* __restrict__ meta) {
  int isb = flags[0];
  int pos = blockIdx.x * 256 + threadIdx.x;
  if (pos >= meta[8]) return;
  int e = perm[pos];
  int tile = pos >> 4, r = pos & 15;
  union U8 { ushort_t s[8]; uint4 u; };
  if (isb) {
    const uint4* p = (const uint4*)((const ushort_t*)eattr + (size_t)e * 16);
    uint4 h0 = p[0], h1 = p[1];
    ((uint4*)phi)[tile * 32 + r] = h0;
    ((uint4*)phi)[tile * 32 + 16 + r] = h1;
  } else {
    const float4* p = (const float4*)((const float*)eattr + (size_t)e * 16);
    U8 hi[2], lo[2];
    #pragma unroll
    for (int q = 0; q < 4; q++) {
      float4 v = p[q];
      float vv[4] = {v.x, v.y, v.z, v.w};
      #pragma unroll
      for (int j = 0; j < 4; j++) {
        int idx = q * 4 + j;
        ushort_t hb = f2b(vv[j]);
        hi[idx >> 3].s[idx & 7] = hb;
        lo[idx >> 3].s[idx & 7] = f2b(vv[j] - b2f(hb));
      }
    }
    ((uint4*)phi)[tile * 32 + r] = hi[0].u;
    ((uint4*)phi)[tile * 32 + 16 + r] = hi[1].u;
    ((uint4*)plo)[tile * 32 + r] = lo[0].u;
    ((uint4*)plo)[tile * 32 + 16 + r] = lo[1].u;
  }
}

// per-layer edge pass: BARRIER-FREE (R9-verified body). Each wave owns 32
// edges (2 sub-tiles of 16): MFMA e=eattr@edge_W into wave-private LDS,
// indices in registers via __shfl, register run-accumulate, atomic flush per
// dst-run. XCD-affine bucket mapping keeps h-gather in each XCD's L2 slice.
__global__ void __launch_bounds__(256) edge_mfma(
    const ushort_t* __restrict__ phi, const ushort_t* __restrict__ plo,
    const uint2* __restrict__ sdp,
    const uint4* __restrict__ wfrag, const float* __restrict__ h,
    float* __restrict__ agg, const int* __restrict__ flags,
    const int* __restrict__ meta) {
  __shared__ float es[4][16 * 68];  // wave-private sub-tile buffer (17.4KB)
  int A[9];
  #pragma unroll
  for (int b = 0; b < 9; b++) A[b] = meta[b];
  int maxcb = 0;
  #pragma unroll
  for (int b = 0; b < NBUCK; b++) {
    int cb = (A[b + 1] - A[b]) >> 7;
    maxcb = cb > maxcb ? cb : maxcb;
  }
  int chunk;
  if (maxcb <= SLOTS) {  // bucket b -> blocks with blockIdx % 8 == b (XCD-affine)
    int xcd = blockIdx.x & 7, s = blockIdx.x >> 3;
    if (s >= ((A[xcd + 1] - A[xcd]) >> 7)) return;
    chunk = (A[xcd] >> 7) + s;
  } else {  // degenerate skew: identity mapping (correctness path)
    chunk = blockIdx.x;
    if (chunk * 128 >= A[8]) return;
  }
  int isb = flags[0];
  int t = threadIdx.x;
  int w = t >> 6, lane = t & 63, kg = lane >> 4, cr = lane & 15;
  int ebase = chunk * 128 + w * 32;  // this wave's 32 edges
  // index registers: lanes 0-31 hold src, lanes 32-63 hold dst (same 32 edges)
  int li = lane & 31;
  const uint_t* sdw = (const uint_t*)sdp;
  int vidx = (int)sdw[2 * (ebase + li) + (lane < 32 ? 0 : 1)];
  union FR { uint4 u; bf16x8 v; };
  FR bh[4], bl[4];
  #pragma unroll
  for (int nt = 0; nt < 4; nt++) bh[nt].u = wfrag[nt * 64 + lane];
  if (!isb) {
    #pragma unroll
    for (int nt = 0; nt < 4; nt++) bl[nt].u = wfrag[256 + nt * 64 + lane];
  }
  const float* ebias = (const float*)(wfrag + 512);
  float bv[4];
  #pragma unroll
  for (int nt = 0; nt < 4; nt++) bv[nt] = ebias[nt * 16 + cr];
  int c = lane;
  float accr = 0.f;
  int cur = -1;
  #pragma unroll
  for (int st = 0; st < 2; st++) {
    int tile = chunk * 8 + w * 2 + st;
    FR ahi, alo;
    ahi.u = make_uint4(0u, 0u, 0u, 0u);
    alo.u = ahi.u;
    if (kg < 2) {
      ahi.u = ((const uint4*)phi)[tile * 32 + kg * 16 + cr];
      if (!isb) alo.u = ((const uint4*)plo)[tile * 32 + kg * 16 + cr];
    }
    f32x4 acc[4];
    #pragma unroll
    for (int nt = 0; nt < 4; nt++) acc[nt] = (f32x4){0.f, 0.f, 0.f, 0.f};
    #pragma unroll
    for (int nt = 0; nt < 4; nt++) {
      acc[nt] = __builtin_amdgcn_mfma_f32_16x16x32_bf16(ahi.v, bh[nt].v, acc[nt], 0, 0, 0);
      if (!isb) {
        acc[nt] = __builtin_amdgcn_mfma_f32_16x16x32_bf16(ahi.v, bl[nt].v, acc[nt], 0, 0, 0);
        acc[nt] = __builtin_amdgcn_mfma_f32_16x16x32_bf16(alo.v, bh[nt].v, acc[nt], 0, 0, 0);
      }
    }
    // drain prior sub-tile's es reads before overwrite (wave-local ordering)
    asm volatile("s_waitcnt lgkmcnt(0)" ::: "memory");
    __builtin_amdgcn_sched_barrier(0);
    // C layout: col = lane&15, row = (lane>>4)*4 + r -> es[edge][chan], stride 68
    // (write banks (16*kg + cr)%32 = exact 2-way -> conflict-free)
    #pragma unroll
    for (int nt = 0; nt < 4; nt++) {
      #pragma unroll
      for (int r = 0; r < 4; r++)
        es[w][(kg * 4 + r) * 68 + nt * 16 + cr] = acc[nt][r] + bv[nt];
    }
    asm volatile("s_waitcnt lgkmcnt(0)" ::: "memory");
    __builtin_amdgcn_sched_barrier(0);
    // gather h rows (16 independent loads in flight)
    float hv[16];
    #pragma unroll
    for (int i = 0; i < 16; i++) {
      int sn = __shfl(vidx, st * 16 + i, 64);
      hv[i] = h[(size_t)sn * 64 + c];
    }
    #pragma unroll
    for (int i = 0; i < 16; i++) {
      int dn = __shfl(vidx, 32 + st * 16 + i, 64);
      float m = hv[i] + es[w][i * 68 + c];
      m = m > 0.f ? m : 0.f;
      if (dn != cur) {  // wave-uniform
        if (cur >= 0 && cur < NN) atomicAdd(&agg[cur * 64 + c], accr);
        cur = dn; accr = 0.f;
      }
      accr += m;
    }
  }
  if (cur >= 0 && cur < NN) atomicAdd(&agg[cur * 64 + c], accr);
}

// sorted edge pass (fallback when scratch can't hold packed eattr).
__global__ void __launch_bounds__(256) edge_sorted(
    const void* __restrict__ eattr, const int* __restrict__ perm,
    const uint2* __restrict__ sdp,
    const void* __restrict__ eW, const void* __restrict__ eb,
    const float* __restrict__ h, float* __restrict__ agg,
    const int* __restrict__ flags, const int* __restrict__ meta) {
  __shared__ float ea[64 * 16];
  __shared__ int ss[64], sdv[64];
  int isb = flags[0];
  int t = threadIdx.x;
  int base = blockIdx.x * 64;
  if (base >= meta[8]) return;
  if (t < 64) {
    uint2 r = sdp[base + t];
    ss[t] = (int)r.x;
    sdv[t] = (int)r.y;
  }
  {
    int slot = t >> 2, q = t & 3;
    int pe = perm[base + slot];
    if (isb) {
      const uint2* p = (const uint2*)((const ushort_t*)eattr + (size_t)pe * 16 + q * 4);
      uint2 u = *p;
      ea[slot * 16 + q * 4 + 0] = b2f((ushort_t)(u.x & 0xffffu));
      ea[slot * 16 + q * 4 + 1] = b2f((ushort_t)(u.x >> 16));
      ea[slot * 16 + q * 4 + 2] = b2f((ushort_t)(u.y & 0xffffu));
      ea[slot * 16 + q * 4 + 3] = b2f((ushort_t)(u.y >> 16));
    } else {
      const float4* p = (const float4*)((const float*)eattr + (size_t)pe * 16 + q * 4);
      float4 v = *p;
      ea[slot * 16 + q * 4 + 0] = v.x;
      ea[slot * 16 + q * 4 + 1] = v.y;
      ea[slot * 16 + q * 4 + 2] = v.z;
      ea[slot * 16 + q * 4 + 3] = v.w;
    }
  }
  int c = t & 63, s0 = t >> 6;
  float w[16];
  #pragma unroll
  for (int k = 0; k < 16; k++) w[k] = LDF(eW, k * 64 + c, isb);
  float bc = LDF(eb, c, isb);
  __syncthreads();
  float acc = 0.f;
  int cur = -1;
  for (int i = 0; i < 16; i++) {
    int slot = s0 * 16 + i;
    int sn = ss[slot], dn = sdv[slot];
    float e = bc;
    #pragma unroll
    for (int k = 0; k < 16; k++) e += ea[slot * 16 + k] * w[k];
    float m = h[sn * 64 + c] + e;
    m = m > 0.f ? m : 0.f;
    if (dn != cur) {  // wave-uniform
      if (cur >= 0 && cur < NN) atomicAdd(&agg[cur * 64 + c], acc);
      cur = dn; acc = 0.f;
    }
    acc += m;
  }
  if (cur >= 0 && cur < NN) atomicAdd(&agg[cur * 64 + c], acc);
}

// ---- weight prepack (once per call): fragment-ordered, coalesced-readable ----
// Layout per layer (uint4 units): w1hi[1024] | w1lo[1024] | w2hi[1024] | w2lo[1024]
// Block 3 packs edge_W B-fragments (4 n-tiles, K=16 zero-padded to 32) + edge bias
// at wpk + 3*4096: hi[256] | lo[256] | ebias f32[64].
__global__ void __launch_bounds__(256) prep_w(
    const void* __restrict__ W1s, const void* __restrict__ W2s,
    const void* __restrict__ eW, const void* __restrict__ eB,
    uint4* __restrict__ wpk, const int* __restrict__ flags) {
  int l = blockIdx.x, t = threadIdx.x, isb = flags[0];
  union U8 { ushort_t s[8]; uint4 u; };
  if (l == 3) {
    uint4* wfrag = wpk + 3 * 4096;
    int nt = t >> 6, lane = t & 63;
    int col = nt * 16 + (lane & 15);
    U8 hi, lo;
    #pragma unroll
    for (int j = 0; j < 8; j++) {
      int k = (lane >> 4) * 8 + j;
      float wf = (k < 16) ? LDF(eW, k * 64 + col, isb) : 0.f;
      ushort_t hb = f2b(wf);
      hi.s[j] = hb;
      lo.s[j] = f2b(wf - b2f(hb));
    }
    wfrag[nt * 64 + lane] = hi.u;
    wfrag[256 + nt * 64 + lane] = lo.u;
    if (t < 64) ((float*)(wfrag + 512))[t] = LDF(eB, t, isb);
    return;
  }
  uint4* w1hi = wpk + (size_t)l * 4096;
  uint4* w1lo = w1hi + 1024;
  uint4* w2hi = w1hi + 2048;
  uint4* w2lo = w1hi + 3072;
  for (int o = t; o < 1024; o += 256) {
    int lane = o & 63, f = (o >> 6) & 7, hh = o >> 9;
    int q = lane >> 4, m = lane & 15;
    {
      int kc = f >> 2, i = f & 3;
      U8 hi, lo;
      #pragma unroll
      for (int j = 0; j < 8; j++) {
        int idx = l * 8192 + (kc * 32 + q * 8 + j) * 128 + (hh * 4 + i) * 16 + m;
        float wf = LDF(W1s, idx, isb);
        ushort_t hb = f2b(wf);
        hi.s[j] = hb;
        lo.s[j] = f2b(wf - b2f(hb));
      }
      w1hi[o] = hi.u;
      w1lo[o] = lo.u;
    }
    {
      int kc = f >> 1, i = f & 1;
      U8 hi, lo;
      #pragma unroll
      for (int j = 0; j < 8; j++) {
        int idx = l * 8192 + (kc * 32 + q * 8 + j) * 64 + (hh * 2 + i) * 16 + m;
        float wf = LDF(W2s, idx, isb);
        ushort_t hb = f2b(wf);
        hi.s[j] = hb;
        lo.s[j] = f2b(wf - b2f(hb));
      }
      w2hi[o] = hi.u;
      w2lo[o] = lo.u;
    }
  }
}

// ---------------- MFMA MLP + BN stats (R5-verified body, packed weights) ----
__global__ void __launch_bounds__(256) mlp_mfma(
    const float* __restrict__ h, const float* agg,
    const uint4* __restrict__ wpk, const void* __restrict__ b1s,
    const void* __restrict__ b2s,
    float* z2out, float* __restrict__ bnsum, const int* __restrict__ flags, int layer) {
  __shared__ uint_t zs[32 * 65];    // packed hi|lo of z, stride 65
  __shared__ uint_t a1s[32 * 129];  // packed hi|lo of a1, stride 129
  int isb = flags[0];
  int t = threadIdx.x;
  int w = t >> 6, lane = t & 63, q = lane >> 4, m = lane & 15;
  int mt = w & 1;             // m-tile for both phases
  int hh = w >> 1;            // n-half for both phases
  int ng1 = hh * 4;           // phase1: 4 n-tiles (of 8)
  int ng2 = hh * 2;           // phase2: 2 n-tiles (of 4)
  int b1off = layer * 128, b2off = layer * 64;
  const uint4* w1hi = wpk + (size_t)layer * 4096;
  const uint4* w1lo = w1hi + 1024;
  const uint4* w2hi = w1hi + 2048;
  const uint4* w2lo = w1hi + 3072;

  union FR { uint4 u; bf16x8 v; };
  FR w1f[4][2], w2f[2][4];
  #pragma unroll
  for (int kc = 0; kc < 2; kc++)
    #pragma unroll
    for (int i = 0; i < 4; i++)
      w1f[i][kc].u = w1hi[(hh * 8 + kc * 4 + i) * 64 + lane];
  #pragma unroll
  for (int kc = 0; kc < 4; kc++)
    #pragma unroll
    for (int i = 0; i < 2; i++)
      w2f[i][kc].u = w2hi[(hh * 8 + kc * 2 + i) * 64 + lane];

  float b1v[4], b2v[2];
  #pragma unroll
  for (int i = 0; i < 4; i++) b1v[i] = LDF(b1s, b1off + (ng1 + i) * 16 + m, isb);
  #pragma unroll
  for (int i = 0; i < 2; i++) b2v[i] = LDF(b2s, b2off + (ng2 + i) * 16 + m, isb);

  int srow = t >> 3, scol = (t & 7) * 8;  // staging role: 8 elems of one row
  float ps[2] = {0.f, 0.f}, pq[2] = {0.f, 0.f};

  for (int tile = blockIdx.x; tile < NTILES; tile += gridDim.x) {
    int base = tile * 32;
    __syncthreads();
    {
      int gr = base + srow;
      if (gr < NN) {
        const float4* hp = (const float4*)(h + (size_t)gr * 64 + scol);
        const float4* ap = (const float4*)(agg + (size_t)gr * 64 + scol);
        float4 h0 = hp[0], h1 = hp[1], a0 = ap[0], a1 = ap[1];
        zs[srow * 65 + scol + 0] = packsplit(h0.x + a0.x);
        zs[srow * 65 + scol + 1] = packsplit(h0.y + a0.y);
        zs[srow * 65 + scol + 2] = packsplit(h0.z + a0.z);
        zs[srow * 65 + scol + 3] = packsplit(h0.w + a0.w);
        zs[srow * 65 + scol + 4] = packsplit(h1.x + a1.x);
        zs[srow * 65 + scol + 5] = packsplit(h1.y + a1.y);
        zs[srow * 65 + scol + 6] = packsplit(h1.z + a1.z);
        zs[srow * 65 + scol + 7] = packsplit(h1.w + a1.w);
      } else {
        #pragma unroll
        for (int jj = 0; jj < 8; jj++) zs[srow * 65 + scol + jj] = 0;
      }
    }
    __syncthreads();
    // phase 1: A(16x64) @ W1(64x128) for this wave's m-tile & 4 n-tiles
    f32x4 acc1[4];
    #pragma unroll
    for (int i = 0; i < 4; i++) acc1[i] = (f32x4){0.f, 0.f, 0.f, 0.f};
    #pragma unroll
    for (int kc = 0; kc < 2; kc++) {
      int ab = (mt * 16 + m) * 65 + kc * 32 + q * 8;
      bf16x8 ahi, alo;
      #pragma unroll
      for (int j = 0; j < 8; j++) {
        uint_t u = zs[ab + j];
        ahi[j] = (short)(u & 0xffffu);
        alo[j] = (short)(u >> 16);
      }
      #pragma unroll
      for (int i = 0; i < 4; i++) {
        acc1[i] = __builtin_amdgcn_mfma_f32_16x16x32_bf16(ahi, w1f[i][kc].v, acc1[i], 0, 0, 0);
        acc1[i] = __builtin_amdgcn_mfma_f32_16x16x32_bf16(alo, w1f[i][kc].v, acc1[i], 0, 0, 0);
        if (!isb) {  // f32 weights: add Ahi * Blo correction (packed lo frag)
          FR bl;
          bl.u = w1lo[(hh * 8 + kc * 4 + i) * 64 + lane];
          acc1[i] = __builtin_amdgcn_mfma_f32_16x16x32_bf16(ahi, bl.v, acc1[i], 0, 0, 0);
        }
      }
    }
    // bias + relu + split-pack into a1s
    #pragma unroll
    for (int i = 0; i < 4; i++) {
      #pragma unroll
      for (int r = 0; r < 4; r++) {
        float v = acc1[i][r] + b1v[i];
        v = v > 0.f ? v : 0.f;
        a1s[(mt * 16 + q * 4 + r) * 129 + (ng1 + i) * 16 + m] = packsplit(v);
      }
    }
    __syncthreads();
    // phase 2: A1(16x128) @ W2(128x64) for this wave's m-tile & 2 n-tiles
    f32x4 acc2[2];
    #pragma unroll
    for (int i = 0; i < 2; i++) acc2[i] = (f32x4){0.f, 0.f, 0.f, 0.f};
    #pragma unroll
    for (int kc = 0; kc < 4; kc++) {
      int ab = (mt * 16 + m) * 129 + kc * 32 + q * 8;
      bf16x8 ahi, alo;
      #pragma unroll
      for (int j = 0; j < 8; j++) {
        uint_t u = a1s[ab + j];
        ahi[j] = (short)(u & 0xffffu);
        alo[j] = (short)(u >> 16);
      }
      #pragma unroll
      for (int i = 0; i < 2; i++) {
        acc2[i] = __builtin_amdgcn_mfma_f32_16x16x32_bf16(ahi, w2f[i][kc].v, acc2[i], 0, 0, 0);
        acc2[i] = __builtin_amdgcn_mfma_f32_16x16x32_bf16(alo, w2f[i][kc].v, acc2[i], 0, 0, 0);
        if (!isb) {
          FR bl;
          bl.u = w2lo[(hh * 8 + kc * 2 + i) * 64 + lane];
          acc2[i] = __builtin_amdgcn_mfma_f32_16x16x32_bf16(ahi, bl.v, acc2[i], 0, 0, 0);
        }
      }
    }
    // write z2 + accumulate BN partials (row-guarded)
    #pragma unroll
    for (int i = 0; i < 2; i++) {
      int col = (ng2 + i) * 16 + m;
      #pragma unroll
      for (int r = 0; r < 4; r++) {
        int gr = base + mt * 16 + q * 4 + r;
        if (gr < NN) {
          float v = acc2[i][r] + b2v[i];
          z2out[(size_t)gr * 64 + col] = v;
          ps[i] += v; pq[i] += v * v;
        }
      }
    }
  }
  // block-level BN reduction, then one global atomic per channel pair
  __syncthreads();
  float* red = (float*)zs;
  if (t < 128) red[t] = 0.f;
  __syncthreads();
  #pragma unroll
  for (int i = 0; i < 2; i++) {
    int col = (ng2 + i) * 16 + m;
    atomicAdd(&red[col], ps[i]);
    atomicAdd(&red[64 + col], pq[i]);
  }
  __syncthreads();
  if (t < 128) atomicAdd(&bnsum[t], red[t]);
}

__global__ void bn_fin(const float* __restrict__ bnsum, const void* __restrict__ gammas,
                       const void* __restrict__ betas, float* __restrict__ scsh,
                       const int* __restrict__ flags, int layer) {
  int c = threadIdx.x;  // 64
  int isb = flags[0];
  float inv_n = 1.0f / (float)NN;
  float mu = bnsum[c] * inv_n;
  float var = bnsum[64 + c] * inv_n - mu * mu;
  var = var > 0.f ? var : 0.f;
  float sc = LDF(gammas, layer * 64 + c, isb) * rsqrtf(var + BN_EPS);
  scsh[c] = sc;
  scsh[64 + c] = LDF(betas, layer * 64 + c, isb) - mu * sc;
}

__global__ void __launch_bounds__(256) bn_apply(
    const float* __restrict__ z2, const float* __restrict__ scsh, float* __restrict__ h) {
  int t = blockIdx.x * 256 + threadIdx.x;
  if (t < NN * 16) {
    float4 z = ((const float4*)z2)[t];
    int c4 = t & 15;
    float4 sc = ((const float4*)scsh)[c4];
    float4 sh = ((const float4*)(scsh + 64))[c4];
    float4 r;
    r.x = fmaxf(z.x * sc.x + sh.x, 0.f);
    r.y = fmaxf(z.y * sc.y + sh.y, 0.f);
    r.z = fmaxf(z.z * sc.z + sh.z, 0.f);
    r.w = fmaxf(z.w * sc.w + sh.w, 0.f);
    ((float4*)h)[t] = r;
  }
}

// batch is sorted: bounds[g] = first i with batch[i] >= g; bounds[NG] = NN.
__global__ void __launch_bounds__(256) find_bounds(
    const void* __restrict__ batch, int* __restrict__ bounds, const int* __restrict__ flags) {
  int is64 = flags[1];
  int i = blockIdx.x * 256 + threadIdx.x;
  if (i >= NN) return;
  int cur = clampi(LDI(batch, i, is64), NG);
  if (i == 0) {
    for (int g = 0; g <= cur; g++) bounds[g] = 0;
  } else {
    int prev = clampi(LDI(batch, i - 1, is64), NG);
    for (int g = prev + 1; g <= cur; g++) bounds[g] = i;
  }
  if (i == NN - 1) {
    for (int g = cur + 1; g <= NG; g++) bounds[g] = NN;
  }
}

__global__ void __launch_bounds__(256) pool_final(
    const float* __restrict__ h, const int* __restrict__ bounds,
    const void* __restrict__ linW, const void* __restrict__ linB,
    float* __restrict__ out, const int* __restrict__ flags) {
  __shared__ float red[4][64];
  int isb = flags[0];
  int g = blockIdx.x;
  int t = threadIdx.x, c = t & 63, w = t >> 6;
  int s = bounds[g], e = bounds[g + 1];
  float acc = 0.f;
  for (int i = s + w; i < e; i += 4) acc += h[i * 64 + c];
  red[w][c] = acc;
  __syncthreads();
  if (t < 64) {
    float v = red[0][c] + red[1][c] + red[2][c] + red[3][c];
    float cnt = (float)(e - s); if (cnt < 1.f) cnt = 1.f;
    v = (v / cnt) * LDF(linW, c, isb);
    #pragma unroll
    for (int m = 32; m >= 1; m >>= 1) v += __shfl_xor(v, m, 64);
    if (c == 0) out[g] = v + LDF(linB, 0, isb);
  }
}

extern "C" void kernel_launch(void* const* d_in, const int* in_sizes, int n_in,
                              void* d_out, int out_size, void* d_ws, size_t ws_size,
                              hipStream_t stream) {
  const void* x     = d_in[0];
  const void* eattr = d_in[1];
  const void* eidx  = d_in[2];
  const void* batch = d_in[3];
  const void* nodeW = d_in[4];
  const void* nodeB = d_in[5];
  const void* edgeW = d_in[6];
  const void* edgeB = d_in[7];
  const void* W1s   = d_in[8];
  const void* b1s   = d_in[9];
  const void* W2s   = d_in[10];
  const void* b2s   = d_in[11];
  const void* gam   = d_in[12];
  const void* bet   = d_in[13];
  const void* linW  = d_in[14];
  const void* linB  = d_in[15];
  float* out = (float*)d_out;

  int*   flags  = (int*)d_ws;              // 16
  int*   meta   = flags + 16;              // 48
  float* h      = (float*)(meta + 48);
  float* agg    = h + (size_t)NN * HD;
  float* bnsum  = agg + (size_t)NN * HD;   // 128
  float* scsh   = bnsum + 128;             // 128
  int*   bounds = (int*)(scsh + 128);      // 80 slots
  int*   csum   = bounds + 80;             // NCHUNK
  int*   cbase  = csum + NCHUNK;           // NCHUNK
  int*   offs   = cbase + NCHUNK;          // NBINS (hist)
  int*   cursor = offs + NBINS;            // NBINS (starts)
  int*   perm   = cursor + NBINS;          // NEP
  uint2* sdp    = (uint2*)(perm + NEP);    // NEP uint2 (8B-aligned: even word off)

  size_t base_words = 64ull + 2ull * NN * HD + 128 + 128 + 80
                    + 2ull * NCHUNK + 2ull * NBINS + 3ull * NEP;
  size_t wpk_words_start = (base_words + 3ull) & ~3ull;  // 16B-align for uint4
  size_t wpk_words = (3ull * 4096 + 528) * 4;            // 3 layers + edge wfrag/bias
  size_t needed = (wpk_words_start + wpk_words) * 4ull;
  if (ws_size < needed) return;  // avoid faulting if scratch too small
  uint4* wpk = (uint4*)((float*)d_ws + wpk_words_start);
  uint4* wfrag = wpk + 3ull * 4096;
  // un-alias z2 from agg when scratch allows (kernel is alias-safe either way)
  size_t z2_start = wpk_words_start + wpk_words;
  float* z2sep = (float*)d_ws + z2_start;
  int have_z2 = ws_size >= (z2_start + (size_t)NN * HD) * 4ull;
  float* z2 = have_z2 ? z2sep : agg;
  // packed sorted eattr MFMA fragments (hi + lo), used when scratch allows
  size_t pat_start = z2_start + (size_t)NN * HD;
  size_t pat_words = (size_t)NEP * 8;  // NEP*16 bf16 = NEP*8 words each
  int have_pat = have_z2 && (ws_size >= (pat_start + 2ull * pat_words) * 4ull);
  ushort_t* phi = (ushort_t*)((float*)d_ws + pat_start);
  ushort_t* plo = (ushort_t*)((float*)d_ws + pat_start + pat_words);

  detect_k<<<1, 64, 0, stream>>>((const uint_t*)x, (const uint_t*)eidx, flags);
  prep_w<<<4, 256, 0, stream>>>(W1s, W2s, edgeW, edgeB, wpk, flags);
  node_embed<<<(NN + 63) / 64, 256, 0, stream>>>(x, nodeW, nodeB, h, flags);

  hipMemsetAsync(offs, 0, (size_t)NBINS * sizeof(int), stream);
  hist_k<<<NE / 256, 256, 0, stream>>>(eidx, offs, flags);
  scan_a<<<NCHUNK, 256, 0, stream>>>(offs, csum);
  scan_b<<<1, 256, 0, stream>>>(csum, cbase, meta);
  scan_c<<<NCHUNK, 256, 0, stream>>>(offs, cbase, cursor);
  pad_fill<<<1, 64, 0, stream>>>(meta, perm, sdp);
  scatter_k<<<NE / 256, 256, 0, stream>>>(eidx, cursor, perm, sdp, flags);
  if (have_pat)
    pack_eattr<<<NEP / 256, 256, 0, stream>>>(eattr, perm, phi, plo, flags, meta);

  for (int l = 0; l < 3; l++) {
    hipMemsetAsync(agg, 0, (size_t)NN * HD * sizeof(float), stream);
    if (have_pat)
      edge_mfma<<<8 * SLOTS, 256, 0, stream>>>(phi, plo, sdp, wfrag, h, agg, flags, meta);
    else
      edge_sorted<<<NEP / 64, 256, 0, stream>>>(eattr, perm, sdp, edgeW, edgeB, h, agg, flags, meta);
    hipMemsetAsync(bnsum, 0, 128 * sizeof(int), stream);
    mlp_mfma<<<784, 256, 0, stream>>>(h, agg, wpk, b1s, b2s, z2, bnsum, flags, l);
    bn_fin<<<1, 64, 0, stream>>>(bnsum, gam, bet, scsh, flags, l);
    bn_apply<<<3125, 256, 0, stream>>>(z2, scsh, h);
  }
  find_bounds<<<(NN + 255) / 256, 256, 0, stream>>>(batch, bounds, flags);
  pool_final<<<NG, 256, 0, stream>>>(h, bounds, linW, linB, out, flags);
}

// Round 20
// 905.809 us; speedup vs baseline: 1.0273x; 1.0273x over previous
//
#include <hip/hip_runtime.h>

#define NN 50000
#define NE 1600000
#define NG 64
#define HD 64
#define BN_EPS 1e-5f
#define NTILES ((NN + 31) / 32)
#define NBUCK 8
#define NPB 6250                 // NN / NBUCK exactly
#define NBINS (NBUCK * NN)       // 400000
#define NEP (NE + 2048)          // padded edge array length (8 buckets x 127 max)
#define SLOTS 1792               // per-XCD 128-edge chunk slots for edge pass
#define CHUNK 2000               // bins per scan chunk (NN % CHUNK == 0)
#define NCHUNK (NBINS / CHUNK)   // 200
#define CPB (NCHUNK / NBUCK)     // 25 chunks per bucket

typedef unsigned short ushort_t;
typedef unsigned int uint_t;
typedef __attribute__((ext_vector_type(8))) short bf16x8;
typedef __attribute__((ext_vector_type(4))) float f32x4;

__device__ __forceinline__ float b2f(ushort_t u) {
  union { uint_t i; float f; } v; v.i = ((uint_t)u) << 16; return v.f;
}
__device__ __forceinline__ ushort_t f2b(float f) {
  union { float f; uint_t i; } v; v.f = f;
  uint_t x = v.i;
  return (ushort_t)((x + 0x7fffu + ((x >> 16) & 1u)) >> 16);
}
// pack f32 into (bf16_hi | bf16_lo<<16); hi+lo reconstructs f to ~2^-17 rel
__device__ __forceinline__ uint_t packsplit(float f) {
  ushort_t hi = f2b(f);
  float r = f - b2f(hi);
  ushort_t lo = f2b(r);
  return (uint_t)hi | ((uint_t)lo << 16);
}
__device__ __forceinline__ float LDF(const void* p, int i, int isb) {
  return isb ? b2f(((const ushort_t*)p)[i]) : ((const float*)p)[i];
}
__device__ __forceinline__ int LDI(const void* p, int i, int is64) {
  return is64 ? ((const int*)p)[2 * i] : ((const int*)p)[i];
}
__device__ __forceinline__ int clampi(int v, int hi) {
  return (v < 0) ? 0 : (v >= hi ? hi - 1 : v);
}

// Sniff dtypes from bit patterns (bf16 exp-byte clustering; int64 high words zero).
__global__ void detect_k(const uint_t* __restrict__ xw, const uint_t* __restrict__ ew,
                         int* __restrict__ flags) {
  int t = threadIdx.x;  // 64 threads
  uint_t w = xw[t];
  uint_t b = (w >> 8) & 0x7fu;
  unsigned long long m1 = __ballot(b >= 0x3au && b <= 0x42u);
  unsigned long long m2 = __ballot(ew[2 * t + 1] == 0u);
  if (t == 0) {
    flags[0] = (__popcll(m1) >= 32) ? 1 : 0;
    flags[1] = (__popcll(m2) >= 56) ? 1 : 0;
  }
}

__global__ void __launch_bounds__(256) node_embed(
    const void* __restrict__ x, const void* __restrict__ W,
    const void* __restrict__ b, float* __restrict__ h, const int* __restrict__ flags) {
  __shared__ float xs[64 * 32];
  int isb = flags[0];
  int t = threadIdx.x;
  int base = blockIdx.x * 64;
  int nodes = NN - base; if (nodes > 64) nodes = 64;
  int idx = t * 8;
  if (idx < nodes * 32) {
    if (isb) {
      const uint4* p = (const uint4*)((const ushort_t*)x + base * 32);
      uint4 u = p[t];
      ushort_t* pu = (ushort_t*)&u;
      #pragma unroll
      for (int q = 0; q < 8; q++) xs[idx + q] = b2f(pu[q]);
    } else {
      const float4* p = (const float4*)((const float*)x + base * 32);
      float4 a = p[2 * t], d = p[2 * t + 1];
      xs[idx + 0] = a.x; xs[idx + 1] = a.y; xs[idx + 2] = a.z; xs[idx + 3] = a.w;
      xs[idx + 4] = d.x; xs[idx + 5] = d.y; xs[idx + 6] = d.z; xs[idx + 7] = d.w;
    }
  }
  int c = t & 63, s0 = t >> 6;
  float w[32];
  #pragma unroll
  for (int k = 0; k < 32; k++) w[k] = LDF(W, k * 64 + c, isb);
  float bc = LDF(b, c, isb);
  __syncthreads();
  #pragma unroll 4
  for (int i = 0; i < 16; i++) {
    int slot = s0 * 16 + i;
    int node = base + slot;
    if (node < NN) {
      float acc = bc;
      #pragma unroll
      for (int k = 0; k < 32; k++) acc += xs[slot * 32 + k] * w[k];
      h[node * 64 + c] = acc;
    }
  }
}

// ---------- counting sort of edges by (src-bucket, dst) (once per call) ------
__global__ void __launch_bounds__(256) hist_k(
    const void* __restrict__ eidx, int* __restrict__ hist, const int* __restrict__ flags) {
  int is64 = flags[1];
  int e = blockIdx.x * 256 + threadIdx.x;
  if (e >= NE) return;
  int d = clampi(LDI(eidx, NE + e, is64), NN);
  int s = clampi(LDI(eidx, e, is64), NN);
  int bin = (s / NPB) * NN + d;
  atomicAdd(&hist[bin], 1);
}

// ---- hierarchical scan over 400k bins ----
// scan_a: per-chunk sums (200 blocks x 2000 bins).
__global__ void __launch_bounds__(256) scan_a(
    const int* __restrict__ hist, int* __restrict__ csum) {
  __shared__ int red[256];
  int c = blockIdx.x, t = threadIdx.x;
  int s = 0;
  if (t < 250) {
    const int4* h4 = (const int4*)(hist + c * CHUNK) + t * 2;
    int4 a = h4[0], b = h4[1];
    s = a.x + a.y + a.z + a.w + b.x + b.y + b.z + b.w;
  }
  red[t] = s;
  __syncthreads();
  for (int d = 128; d > 0; d >>= 1) {
    if (t < d) red[t] += red[t + d];
    __syncthreads();
  }
  if (t == 0) csum[c] = red[0];
}

// scan_b: bucket totals + 128-aligned starts A[b] + per-chunk bases.
// meta[0..8] = aligned bucket starts (meta[8] = padded total);
// meta[16+b] = real end of bucket b.
__global__ void __launch_bounds__(256) scan_b(
    const int* __restrict__ csum, int* __restrict__ cbase, int* __restrict__ meta) {
  __shared__ int sc[NCHUNK];
  __shared__ int sT[NBUCK];
  __shared__ int sA[NBUCK + 1];
  int t = threadIdx.x;
  if (t < NCHUNK) sc[t] = csum[t];
  __syncthreads();
  if (t < NBUCK) {
    int T = 0;
    for (int i = 0; i < CPB; i++) T += sc[t * CPB + i];
    sT[t] = T;
  }
  __syncthreads();
  if (t == 0) {
    int a = 0;
    for (int b = 0; b < NBUCK; b++) {
      sA[b] = a;
      meta[b] = a;
      meta[16 + b] = a + sT[b];
      a = (a + sT[b] + 127) & ~127;   // 128-edge chunk alignment
    }
    meta[NBUCK] = a;
    sA[NBUCK] = a;
  }
  __syncthreads();
  if (t < NBUCK) {
    int run = sA[t];
    for (int i = 0; i < CPB; i++) { cbase[t * CPB + i] = run; run += sc[t * CPB + i]; }
  }
}

// scan_c: per-chunk exclusive scan, seeded by cbase (200 blocks).
__global__ void __launch_bounds__(256) scan_c(
    const int* __restrict__ hist, const int* __restrict__ cbase,
    int* __restrict__ starts) {
  __shared__ int buf[256];
  int c = blockIdx.x, t = threadIdx.x;
  int4 a = {0, 0, 0, 0}, b = {0, 0, 0, 0};
  int s = 0;
  if (t < 250) {
    const int4* h4 = (const int4*)(hist + c * CHUNK) + t * 2;
    a = h4[0]; b = h4[1];
    s = a.x + a.y + a.z + a.w + b.x + b.y + b.z + b.w;
  }
  buf[t] = s;
  __syncthreads();
  for (int d = 1; d < 256; d <<= 1) {
    int x = (t >= d) ? buf[t - d] : 0;
    __syncthreads();
    buf[t] += x;
    __syncthreads();
  }
  if (t < 250) {
    int run = cbase[c] + buf[t] - s;  // exclusive prefix for this thread's 8 bins
    int4 o1, o2;
    o1.x = run; run += a.x;
    o1.y = run; run += a.y;
    o1.z = run; run += a.z;
    o1.w = run; run += a.w;
    o2.x = run; run += b.x;
    o2.y = run; run += b.y;
    o2.z = run; run += b.z;
    o2.w = run; run += b.w;
    int4* s4 = (int4*)(starts + c * CHUNK) + t * 2;
    s4[0] = o1; s4[1] = o2;
  }
}

// fill pad slots (between real end and aligned end of each bucket)
__global__ void pad_fill(const int* __restrict__ meta, int* __restrict__ perm,
                         int* __restrict__ psrc, int* __restrict__ pdst) {
  int t = threadIdx.x;  // 64
  for (int b = 0; b < NBUCK; b++) {
    int re = meta[16 + b], ae = meta[b + 1];
    for (int p = re + t; p < ae; p += 64) {
      perm[p] = 0; psrc[p] = 0; pdst[p] = NN;
    }
  }
}

// R9-verified scatter: 3 independent 4B stores/edge (measured optimum:
// 3 chains @104us > 2 chains @127us > 1 chain @140us; issue-MLP-bound).
__global__ void __launch_bounds__(256) scatter_k(
    const void* __restrict__ eidx, int* __restrict__ cursor,
    int* __restrict__ perm, int* __restrict__ psrc, int* __restrict__ pdst,
    const int* __restrict__ flags) {
  int is64 = flags[1];
  int e = blockIdx.x * 256 + threadIdx.x;
  if (e >= NE) return;
  int d = clampi(LDI(eidx, NE + e, is64), NN);
  int s = clampi(LDI(eidx, e, is64), NN);
  int bin = (s / NPB) * NN + d;
  int pos = atomicAdd(&cursor[bin], 1);
  perm[pos] = e;
  psrc[pos] = s;
  pdst[pos] = d;
}

// ---- one-time: gather eattr by perm into sorted order, pre-laid-out as
// MFMA A-fragments (bf16 hi + lo split). Per 16-edge tile: 512B hi (+512B lo).
__global__ void __launch_bounds__(256) pack_eattr(
    const void* __restrict__ eattr, const int* __restrict__ perm,
    ushort_t* __restrict__ phi, ushort_t* __restrict__ plo,
    const int* __restrict__ flags, const int* __restrict__ meta) {
  int isb = flags[0];
  int pos = blockIdx.x * 256 + threadIdx.x;
  if (pos >= meta[8]) return;
  int e = perm[pos];
  int tile = pos >> 4, r = pos & 15;
  union U8 { ushort_t s[8]; uint4 u; };
  if (isb) {
    const uint4* p = (const uint4*)((const ushort_t*)eattr + (size_t)e * 16);
    uint4 h0 = p[0], h1 = p[1];
    ((uint4*)phi)[tile * 32 + r] = h0;
    ((uint4*)phi)[tile * 32 + 16 + r] = h1;
  } else {
    const float4* p = (const float4*)((const float*)eattr + (size_t)e * 16);
    U8 hi[2], lo[2];
    #pragma unroll
    for (int q = 0; q < 4; q++) {
      float4 v = p[q];
      float vv[4] = {v.x, v.y, v.z, v.w};
      #pragma unroll
      for (int j = 0; j < 4; j++) {
        int idx = q * 4 + j;
        ushort_t hb = f2b(vv[j]);
        hi[idx >> 3].s[idx & 7] = hb;
        lo[idx >> 3].s[idx & 7] = f2b(vv[j] - b2f(hb));
      }
    }
    ((uint4*)phi)[tile * 32 + r] = hi[0].u;
    ((uint4*)phi)[tile * 32 + 16 + r] = hi[1].u;
    ((uint4*)plo)[tile * 32 + r] = lo[0].u;
    ((uint4*)plo)[tile * 32 + 16 + r] = lo[1].u;
  }
}

// per-layer edge pass: BARRIER-FREE (R9-verified body). Each wave owns 32
// edges (2 sub-tiles of 16): MFMA e=eattr@edge_W into wave-private LDS,
// indices in registers via __shfl, register run-accumulate, atomic flush per
// dst-run. XCD-affine bucket mapping keeps h-gather in each XCD's L2 slice.
__global__ void __launch_bounds__(256) edge_mfma(
    const ushort_t* __restrict__ phi, const ushort_t* __restrict__ plo,
    const int* __restrict__ psrc, const int* __restrict__ pdst,
    const uint4* __restrict__ wfrag, const float* __restrict__ h,
    float* __restrict__ agg, const int* __restrict__ flags,
    const int* __restrict__ meta) {
  __shared__ float es[4][16 * 68];  // wave-private sub-tile buffer (17.4KB)
  int A[9];
  #pragma unroll
  for (int b = 0; b < 9; b++) A[b] = meta[b];
  int maxcb = 0;
  #pragma unroll
  for (int b = 0; b < NBUCK; b++) {
    int cb = (A[b + 1] - A[b]) >> 7;
    maxcb = cb > maxcb ? cb : maxcb;
  }
  int chunk;
  if (maxcb <= SLOTS) {  // bucket b -> blocks with blockIdx % 8 == b (XCD-affine)
    int xcd = blockIdx.x & 7, s = blockIdx.x >> 3;
    if (s >= ((A[xcd + 1] - A[xcd]) >> 7)) return;
    chunk = (A[xcd] >> 7) + s;
  } else {  // degenerate skew: identity mapping (correctness path)
    chunk = blockIdx.x;
    if (chunk * 128 >= A[8]) return;
  }
  int isb = flags[0];
  int t = threadIdx.x;
  int w = t >> 6, lane = t & 63, kg = lane >> 4, cr = lane & 15;
  int ebase = chunk * 128 + w * 32;  // this wave's 32 edges
  // index registers: lanes 0-31 hold psrc, lanes 32-63 hold pdst
  int li = lane & 31;
  int vidx = (lane < 32) ? psrc[ebase + li] : pdst[ebase + li];
  union FR { uint4 u; bf16x8 v; };
  FR bh[4], bl[4];
  #pragma unroll
  for (int nt = 0; nt < 4; nt++) bh[nt].u = wfrag[nt * 64 + lane];
  if (!isb) {
    #pragma unroll
    for (int nt = 0; nt < 4; nt++) bl[nt].u = wfrag[256 + nt * 64 + lane];
  }
  const float* ebias = (const float*)(wfrag + 512);
  float bv[4];
  #pragma unroll
  for (int nt = 0; nt < 4; nt++) bv[nt] = ebias[nt * 16 + cr];
  int c = lane;
  float accr = 0.f;
  int cur = -1;
  #pragma unroll
  for (int st = 0; st < 2; st++) {
    int tile = chunk * 8 + w * 2 + st;
    FR ahi, alo;
    ahi.u = make_uint4(0u, 0u, 0u, 0u);
    alo.u = ahi.u;
    if (kg < 2) {
      ahi.u = ((const uint4*)phi)[tile * 32 + kg * 16 + cr];
      if (!isb) alo.u = ((const uint4*)plo)[tile * 32 + kg * 16 + cr];
    }
    f32x4 acc[4];
    #pragma unroll
    for (int nt = 0; nt < 4; nt++) acc[nt] = (f32x4){0.f, 0.f, 0.f, 0.f};
    #pragma unroll
    for (int nt = 0; nt < 4; nt++) {
      acc[nt] = __builtin_amdgcn_mfma_f32_16x16x32_bf16(ahi.v, bh[nt].v, acc[nt], 0, 0, 0);
      if (!isb) {
        acc[nt] = __builtin_amdgcn_mfma_f32_16x16x32_bf16(ahi.v, bl[nt].v, acc[nt], 0, 0, 0);
        acc[nt] = __builtin_amdgcn_mfma_f32_16x16x32_bf16(alo.v, bh[nt].v, acc[nt], 0, 0, 0);
      }
    }
    // drain prior sub-tile's es reads before overwrite (wave-local ordering)
    asm volatile("s_waitcnt lgkmcnt(0)" ::: "memory");
    __builtin_amdgcn_sched_barrier(0);
    // C layout: col = lane&15, row = (lane>>4)*4 + r -> es[edge][chan], stride 68
    // (write banks (16*kg + cr)%32 = exact 2-way -> conflict-free)
    #pragma unroll
    for (int nt = 0; nt < 4; nt++) {
      #pragma unroll
      for (int r = 0; r < 4; r++)
        es[w][(kg * 4 + r) * 68 + nt * 16 + cr] = acc[nt][r] + bv[nt];
    }
    asm volatile("s_waitcnt lgkmcnt(0)" ::: "memory");
    __builtin_amdgcn_sched_barrier(0);
    // gather h rows (16 independent loads in flight)
    float hv[16];
    #pragma unroll
    for (int i = 0; i < 16; i++) {
      int sn = __shfl(vidx, st * 16 + i, 64);
      hv[i] = h[(size_t)sn * 64 + c];
    }
    #pragma unroll
    for (int i = 0; i < 16; i++) {
      int dn = __shfl(vidx, 32 + st * 16 + i, 64);
      float m = hv[i] + es[w][i * 68 + c];
      m = m > 0.f ? m : 0.f;
      if (dn != cur) {  // wave-uniform
        if (cur >= 0 && cur < NN) atomicAdd(&agg[cur * 64 + c], accr);
        cur = dn; accr = 0.f;
      }
      accr += m;
    }
  }
  if (cur >= 0 && cur < NN) atomicAdd(&agg[cur * 64 + c], accr);
}

// sorted edge pass (fallback when scratch can't hold packed eattr).
__global__ void __launch_bounds__(256) edge_sorted(
    const void* __restrict__ eattr, const int* __restrict__ perm,
    const int* __restrict__ psrc, const int* __restrict__ pdst,
    const void* __restrict__ eW, const void* __restrict__ eb,
    const float* __restrict__ h, float* __restrict__ agg,
    const int* __restrict__ flags, const int* __restrict__ meta) {
  __shared__ float ea[64 * 16];
  __shared__ int ss[64], sd[64];
  int isb = flags[0];
  int t = threadIdx.x;
  int base = blockIdx.x * 64;
  if (base >= meta[8]) return;
  if (t < 64) ss[t] = psrc[base + t];
  else if (t < 128) sd[t - 64] = pdst[base + t - 64];
  {
    int slot = t >> 2, q = t & 3;
    int pe = perm[base + slot];
    if (isb) {
      const uint2* p = (const uint2*)((const ushort_t*)eattr + (size_t)pe * 16 + q * 4);
      uint2 u = *p;
      ea[slot * 16 + q * 4 + 0] = b2f((ushort_t)(u.x & 0xffffu));
      ea[slot * 16 + q * 4 + 1] = b2f((ushort_t)(u.x >> 16));
      ea[slot * 16 + q * 4 + 2] = b2f((ushort_t)(u.y & 0xffffu));
      ea[slot * 16 + q * 4 + 3] = b2f((ushort_t)(u.y >> 16));
    } else {
      const float4* p = (const float4*)((const float*)eattr + (size_t)pe * 16 + q * 4);
      float4 v = *p;
      ea[slot * 16 + q * 4 + 0] = v.x;
      ea[slot * 16 + q * 4 + 1] = v.y;
      ea[slot * 16 + q * 4 + 2] = v.z;
      ea[slot * 16 + q * 4 + 3] = v.w;
    }
  }
  int c = t & 63, s0 = t >> 6;
  float w[16];
  #pragma unroll
  for (int k = 0; k < 16; k++) w[k] = LDF(eW, k * 64 + c, isb);
  float bc = LDF(eb, c, isb);
  __syncthreads();
  float acc = 0.f;
  int cur = -1;
  for (int i = 0; i < 16; i++) {
    int slot = s0 * 16 + i;
    int sn = ss[slot], dn = sd[slot];
    float e = bc;
    #pragma unroll
    for (int k = 0; k < 16; k++) e += ea[slot * 16 + k] * w[k];
    float m = h[sn * 64 + c] + e;
    m = m > 0.f ? m : 0.f;
    if (dn != cur) {  // wave-uniform
      if (cur >= 0 && cur < NN) atomicAdd(&agg[cur * 64 + c], acc);
      cur = dn; acc = 0.f;
    }
    acc += m;
  }
  if (cur >= 0 && cur < NN) atomicAdd(&agg[cur * 64 + c], acc);
}

// ---- weight prepack (once per call): fragment-ordered, coalesced-readable ----
// Layout per layer (uint4 units): w1hi[1024] | w1lo[1024] | w2hi[1024] | w2lo[1024]
// Block 3 packs edge_W B-fragments (4 n-tiles, K=16 zero-padded to 32) + edge bias
// at wpk + 3*4096: hi[256] | lo[256] | ebias f32[64].
__global__ void __launch_bounds__(256) prep_w(
    const void* __restrict__ W1s, const void* __restrict__ W2s,
    const void* __restrict__ eW, const void* __restrict__ eB,
    uint4* __restrict__ wpk, const int* __restrict__ flags) {
  int l = blockIdx.x, t = threadIdx.x, isb = flags[0];
  union U8 { ushort_t s[8]; uint4 u; };
  if (l == 3) {
    uint4* wfrag = wpk + 3 * 4096;
    int nt = t >> 6, lane = t & 63;
    int col = nt * 16 + (lane & 15);
    U8 hi, lo;
    #pragma unroll
    for (int j = 0; j < 8; j++) {
      int k = (lane >> 4) * 8 + j;
      float wf = (k < 16) ? LDF(eW, k * 64 + col, isb) : 0.f;
      ushort_t hb = f2b(wf);
      hi.s[j] = hb;
      lo.s[j] = f2b(wf - b2f(hb));
    }
    wfrag[nt * 64 + lane] = hi.u;
    wfrag[256 + nt * 64 + lane] = lo.u;
    if (t < 64) ((float*)(wfrag + 512))[t] = LDF(eB, t, isb);
    return;
  }
  uint4* w1hi = wpk + (size_t)l * 4096;
  uint4* w1lo = w1hi + 1024;
  uint4* w2hi = w1hi + 2048;
  uint4* w2lo = w1hi + 3072;
  for (int o = t; o < 1024; o += 256) {
    int lane = o & 63, f = (o >> 6) & 7, hh = o >> 9;
    int q = lane >> 4, m = lane & 15;
    {
      int kc = f >> 2, i = f & 3;
      U8 hi, lo;
      #pragma unroll
      for (int j = 0; j < 8; j++) {
        int idx = l * 8192 + (kc * 32 + q * 8 + j) * 128 + (hh * 4 + i) * 16 + m;
        float wf = LDF(W1s, idx, isb);
        ushort_t hb = f2b(wf);
        hi.s[j] = hb;
        lo.s[j] = f2b(wf - b2f(hb));
      }
      w1hi[o] = hi.u;
      w1lo[o] = lo.u;
    }
    {
      int kc = f >> 1, i = f & 1;
      U8 hi, lo;
      #pragma unroll
      for (int j = 0; j < 8; j++) {
        int idx = l * 8192 + (kc * 32 + q * 8 + j) * 64 + (hh * 2 + i) * 16 + m;
        float wf = LDF(W2s, idx, isb);
        ushort_t hb = f2b(wf);
        hi.s[j] = hb;
        lo.s[j] = f2b(wf - b2f(hb));
      }
      w2hi[o] = hi.u;
      w2lo[o] = lo.u;
    }
  }
}

// ---------------- MFMA MLP + BN stats (R5-verified body, packed weights) ----
__global__ void __launch_bounds__(256) mlp_mfma(
    const float* __restrict__ h, const float* agg,
    const uint4* __restrict__ wpk, const void* __restrict__ b1s,
    const void* __restrict__ b2s,
    float* z2out, float* __restrict__ bnsum, const int* __restrict__ flags, int layer) {
  __shared__ uint_t zs[32 * 65];    // packed hi|lo of z, stride 65
  __shared__ uint_t a1s[32 * 129];  // packed hi|lo of a1, stride 129
  int isb = flags[0];
  int t = threadIdx.x;
  int w = t >> 6, lane = t & 63, q = lane >> 4, m = lane & 15;
  int mt = w & 1;             // m-tile for both phases
  int hh = w >> 1;            // n-half for both phases
  int ng1 = hh * 4;           // phase1: 4 n-tiles (of 8)
  int ng2 = hh * 2;           // phase2: 2 n-tiles (of 4)
  int b1off = layer * 128, b2off = layer * 64;
  const uint4* w1hi = wpk + (size_t)layer * 4096;
  const uint4* w1lo = w1hi + 1024;
  const uint4* w2hi = w1hi + 2048;
  const uint4* w2lo = w1hi + 3072;

  union FR { uint4 u; bf16x8 v; };
  FR w1f[4][2], w2f[2][4];
  #pragma unroll
  for (int kc = 0; kc < 2; kc++)
    #pragma unroll
    for (int i = 0; i < 4; i++)
      w1f[i][kc].u = w1hi[(hh * 8 + kc * 4 + i) * 64 + lane];
  #pragma unroll
  for (int kc = 0; kc < 4; kc++)
    #pragma unroll
    for (int i = 0; i < 2; i++)
      w2f[i][kc].u = w2hi[(hh * 8 + kc * 2 + i) * 64 + lane];

  float b1v[4], b2v[2];
  #pragma unroll
  for (int i = 0; i < 4; i++) b1v[i] = LDF(b1s, b1off + (ng1 + i) * 16 + m, isb);
  #pragma unroll
  for (int i = 0; i < 2; i++) b2v[i] = LDF(b2s, b2off + (ng2 + i) * 16 + m, isb);

  int srow = t >> 3, scol = (t & 7) * 8;  // staging role: 8 elems of one row
  float ps[2] = {0.f, 0.f}, pq[2] = {0.f, 0.f};

  for (int tile = blockIdx.x; tile < NTILES; tile += gridDim.x) {
    int base = tile * 32;
    __syncthreads();
    {
      int gr = base + srow;
      if (gr < NN) {
        const float4* hp = (const float4*)(h + (size_t)gr * 64 + scol);
        const float4* ap = (const float4*)(agg + (size_t)gr * 64 + scol);
        float4 h0 = hp[0], h1 = hp[1], a0 = ap[0], a1 = ap[1];
        zs[srow * 65 + scol + 0] = packsplit(h0.x + a0.x);
        zs[srow * 65 + scol + 1] = packsplit(h0.y + a0.y);
        zs[srow * 65 + scol + 2] = packsplit(h0.z + a0.z);
        zs[srow * 65 + scol + 3] = packsplit(h0.w + a0.w);
        zs[srow * 65 + scol + 4] = packsplit(h1.x + a1.x);
        zs[srow * 65 + scol + 5] = packsplit(h1.y + a1.y);
        zs[srow * 65 + scol + 6] = packsplit(h1.z + a1.z);
        zs[srow * 65 + scol + 7] = packsplit(h1.w + a1.w);
      } else {
        #pragma unroll
        for (int jj = 0; jj < 8; jj++) zs[srow * 65 + scol + jj] = 0;
      }
    }
    __syncthreads();
    // phase 1: A(16x64) @ W1(64x128) for this wave's m-tile & 4 n-tiles
    f32x4 acc1[4];
    #pragma unroll
    for (int i = 0; i < 4; i++) acc1[i] = (f32x4){0.f, 0.f, 0.f, 0.f};
    #pragma unroll
    for (int kc = 0; kc < 2; kc++) {
      int ab = (mt * 16 + m) * 65 + kc * 32 + q * 8;
      bf16x8 ahi, alo;
      #pragma unroll
      for (int j = 0; j < 8; j++) {
        uint_t u = zs[ab + j];
        ahi[j] = (short)(u & 0xffffu);
        alo[j] = (short)(u >> 16);
      }
      #pragma unroll
      for (int i = 0; i < 4; i++) {
        acc1[i] = __builtin_amdgcn_mfma_f32_16x16x32_bf16(ahi, w1f[i][kc].v, acc1[i], 0, 0, 0);
        acc1[i] = __builtin_amdgcn_mfma_f32_16x16x32_bf16(alo, w1f[i][kc].v, acc1[i], 0, 0, 0);
        if (!isb) {  // f32 weights: add Ahi * Blo correction (packed lo frag)
          FR bl;
          bl.u = w1lo[(hh * 8 + kc * 4 + i) * 64 + lane];
          acc1[i] = __builtin_amdgcn_mfma_f32_16x16x32_bf16(ahi, bl.v, acc1[i], 0, 0, 0);
        }
      }
    }
    // bias + relu + split-pack into a1s
    #pragma unroll
    for (int i = 0; i < 4; i++) {
      #pragma unroll
      for (int r = 0; r < 4; r++) {
        float v = acc1[i][r] + b1v[i];
        v = v > 0.f ? v : 0.f;
        a1s[(mt * 16 + q * 4 + r) * 129 + (ng1 + i) * 16 + m] = packsplit(v);
      }
    }
    __syncthreads();
    // phase 2: A1(16x128) @ W2(128x64) for this wave's m-tile & 2 n-tiles
    f32x4 acc2[2];
    #pragma unroll
    for (int i = 0; i < 2; i++) acc2[i] = (f32x4){0.f, 0.f, 0.f, 0.f};
    #pragma unroll
    for (int kc = 0; kc < 4; kc++) {
      int ab = (mt * 16 + m) * 129 + kc * 32 + q * 8;
      bf16x8 ahi, alo;
      #pragma unroll
      for (int j = 0; j < 8; j++) {
        uint_t u = a1s[ab + j];
        ahi[j] = (short)(u & 0xffffu);
        alo[j] = (short)(u >> 16);
      }
      #pragma unroll
      for (int i = 0; i < 2; i++) {
        acc2[i] = __builtin_amdgcn_mfma_f32_16x16x32_bf16(ahi, w2f[i][kc].v, acc2[i], 0, 0, 0);
        acc2[i] = __builtin_amdgcn_mfma_f32_16x16x32_bf16(alo, w2f[i][kc].v, acc2[i], 0, 0, 0);
        if (!isb) {
          FR bl;
          bl.u = w2lo[(hh * 8 + kc * 2 + i) * 64 + lane];
          acc2[i] = __builtin_amdgcn_mfma_f32_16x16x32_bf16(ahi, bl.v, acc2[i], 0, 0, 0);
        }
      }
    }
    // write z2 + accumulate BN partials (row-guarded)
    #pragma unroll
    for (int i = 0; i < 2; i++) {
      int col = (ng2 + i) * 16 + m;
      #pragma unroll
      for (int r = 0; r < 4; r++) {
        int gr = base + mt * 16 + q * 4 + r;
        if (gr < NN) {
          float v = acc2[i][r] + b2v[i];
          z2out[(size_t)gr * 64 + col] = v;
          ps[i] += v; pq[i] += v * v;
        }
      }
    }
  }
  // block-level BN reduction, then one global atomic per channel pair
  __syncthreads();
  float* red = (float*)zs;
  if (t < 128) red[t] = 0.f;
  __syncthreads();
  #pragma unroll
  for (int i = 0; i < 2; i++) {
    int col = (ng2 + i) * 16 + m;
    atomicAdd(&red[col], ps[i]);
    atomicAdd(&red[64 + col], pq[i]);
  }
  __syncthreads();
  if (t < 128) atomicAdd(&bnsum[t], red[t]);
}

__global__ void bn_fin(const float* __restrict__ bnsum, const void* __restrict__ gammas,
                       const void* __restrict__ betas, float* __restrict__ scsh,
                       const int* __restrict__ flags, int layer) {
  int c = threadIdx.x;  // 64
  int isb = flags[0];
  float inv_n = 1.0f / (float)NN;
  float mu = bnsum[c] * inv_n;
  float var = bnsum[64 + c] * inv_n - mu * mu;
  var = var > 0.f ? var : 0.f;
  float sc = LDF(gammas, layer * 64 + c, isb) * rsqrtf(var + BN_EPS);
  scsh[c] = sc;
  scsh[64 + c] = LDF(betas, layer * 64 + c, isb) - mu * sc;
}

// BN apply + fused agg-zeroing for the next layer's edge pass (saves the
// 12.8MB hipMemsetAsync for layers 1-2). Alias-safe: z read before agg write.
__global__ void __launch_bounds__(256) bn_apply(
    const float* __restrict__ z2, const float* __restrict__ scsh,
    float* __restrict__ h, float* __restrict__ aggz) {
  int t = blockIdx.x * 256 + threadIdx.x;
  if (t < NN * 16) {
    float4 z = ((const float4*)z2)[t];
    int c4 = t & 15;
    float4 sc = ((const float4*)scsh)[c4];
    float4 sh = ((const float4*)(scsh + 64))[c4];
    float4 r;
    r.x = fmaxf(z.x * sc.x + sh.x, 0.f);
    r.y = fmaxf(z.y * sc.y + sh.y, 0.f);
    r.z = fmaxf(z.z * sc.z + sh.z, 0.f);
    r.w = fmaxf(z.w * sc.w + sh.w, 0.f);
    ((float4*)h)[t] = r;
    ((float4*)aggz)[t] = make_float4(0.f, 0.f, 0.f, 0.f);
  }
}

// batch is sorted: bounds[g] = first i with batch[i] >= g; bounds[NG] = NN.
__global__ void __launch_bounds__(256) find_bounds(
    const void* __restrict__ batch, int* __restrict__ bounds, const int* __restrict__ flags) {
  int is64 = flags[1];
  int i = blockIdx.x * 256 + threadIdx.x;
  if (i >= NN) return;
  int cur = clampi(LDI(batch, i, is64), NG);
  if (i == 0) {
    for (int g = 0; g <= cur; g++) bounds[g] = 0;
  } else {
    int prev = clampi(LDI(batch, i - 1, is64), NG);
    for (int g = prev + 1; g <= cur; g++) bounds[g] = i;
  }
  if (i == NN - 1) {
    for (int g = cur + 1; g <= NG; g++) bounds[g] = NN;
  }
}

__global__ void __launch_bounds__(256) pool_final(
    const float* __restrict__ h, const int* __restrict__ bounds,
    const void* __restrict__ linW, const void* __restrict__ linB,
    float* __restrict__ out, const int* __restrict__ flags) {
  __shared__ float red[4][64];
  int isb = flags[0];
  int g = blockIdx.x;
  int t = threadIdx.x, c = t & 63, w = t >> 6;
  int s = bounds[g], e = bounds[g + 1];
  float acc = 0.f;
  for (int i = s + w; i < e; i += 4) acc += h[i * 64 + c];
  red[w][c] = acc;
  __syncthreads();
  if (t < 64) {
    float v = red[0][c] + red[1][c] + red[2][c] + red[3][c];
    float cnt = (float)(e - s); if (cnt < 1.f) cnt = 1.f;
    v = (v / cnt) * LDF(linW, c, isb);
    #pragma unroll
    for (int m = 32; m >= 1; m >>= 1) v += __shfl_xor(v, m, 64);
    if (c == 0) out[g] = v + LDF(linB, 0, isb);
  }
}

extern "C" void kernel_launch(void* const* d_in, const int* in_sizes, int n_in,
                              void* d_out, int out_size, void* d_ws, size_t ws_size,
                              hipStream_t stream) {
  const void* x     = d_in[0];
  const void* eattr = d_in[1];
  const void* eidx  = d_in[2];
  const void* batch = d_in[3];
  const void* nodeW = d_in[4];
  const void* nodeB = d_in[5];
  const void* edgeW = d_in[6];
  const void* edgeB = d_in[7];
  const void* W1s   = d_in[8];
  const void* b1s   = d_in[9];
  const void* W2s   = d_in[10];
  const void* b2s   = d_in[11];
  const void* gam   = d_in[12];
  const void* bet   = d_in[13];
  const void* linW  = d_in[14];
  const void* linB  = d_in[15];
  float* out = (float*)d_out;

  int*   flags  = (int*)d_ws;              // 16
  int*   meta   = flags + 16;              // 48
  float* h      = (float*)(meta + 48);
  float* agg    = h + (size_t)NN * HD;
  float* bnsum  = agg + (size_t)NN * HD;   // 128
  float* scsh   = bnsum + 128;             // 128
  int*   bounds = (int*)(scsh + 128);      // 80 slots
  int*   csum   = bounds + 80;             // NCHUNK
  int*   cbase  = csum + NCHUNK;           // NCHUNK
  int*   offs   = cbase + NCHUNK;          // NBINS (hist)
  int*   cursor = offs + NBINS;            // NBINS (starts)
  int*   perm   = cursor + NBINS;          // NEP
  int*   psrc   = perm + NEP;              // NEP
  int*   pdst   = psrc + NEP;              // NEP

  size_t base_words = 64ull + 2ull * NN * HD + 128 + 128 + 80
                    + 2ull * NCHUNK + 2ull * NBINS + 3ull * NEP;
  size_t wpk_words_start = (base_words + 3ull) & ~3ull;  // 16B-align for uint4
  size_t wpk_words = (3ull * 4096 + 528) * 4;            // 3 layers + edge wfrag/bias
  size_t needed = (wpk_words_start + wpk_words) * 4ull;
  if (ws_size < needed) return;  // avoid faulting if scratch too small
  uint4* wpk = (uint4*)((float*)d_ws + wpk_words_start);
  uint4* wfrag = wpk + 3ull * 4096;
  // un-alias z2 from agg when scratch allows (kernel is alias-safe either way)
  size_t z2_start = wpk_words_start + wpk_words;
  float* z2sep = (float*)d_ws + z2_start;
  int have_z2 = ws_size >= (z2_start + (size_t)NN * HD) * 4ull;
  float* z2 = have_z2 ? z2sep : agg;
  // packed sorted eattr MFMA fragments (hi + lo), used when scratch allows
  size_t pat_start = z2_start + (size_t)NN * HD;
  size_t pat_words = (size_t)NEP * 8;  // NEP*16 bf16 = NEP*8 words each
  int have_pat = have_z2 && (ws_size >= (pat_start + 2ull * pat_words) * 4ull);
  ushort_t* phi = (ushort_t*)((float*)d_ws + pat_start);
  ushort_t* plo = (ushort_t*)((float*)d_ws + pat_start + pat_words);

  detect_k<<<1, 64, 0, stream>>>((const uint_t*)x, (const uint_t*)eidx, flags);
  prep_w<<<4, 256, 0, stream>>>(W1s, W2s, edgeW, edgeB, wpk, flags);
  node_embed<<<(NN + 63) / 64, 256, 0, stream>>>(x, nodeW, nodeB, h, flags);

  hipMemsetAsync(offs, 0, (size_t)NBINS * sizeof(int), stream);
  hist_k<<<NE / 256, 256, 0, stream>>>(eidx, offs, flags);
  scan_a<<<NCHUNK, 256, 0, stream>>>(offs, csum);
  scan_b<<<1, 256, 0, stream>>>(csum, cbase, meta);
  scan_c<<<NCHUNK, 256, 0, stream>>>(offs, cbase, cursor);
  pad_fill<<<1, 64, 0, stream>>>(meta, perm, psrc, pdst);
  scatter_k<<<NE / 256, 256, 0, stream>>>(eidx, cursor, perm, psrc, pdst, flags);
  if (have_pat)
    pack_eattr<<<NEP / 256, 256, 0, stream>>>(eattr, perm, phi, plo, flags, meta);

  // agg zeroed by memset for layer 0; by fused bn_apply for layers 1-2.
  hipMemsetAsync(agg, 0, (size_t)NN * HD * sizeof(float), stream);
  for (int l = 0; l < 3; l++) {
    if (have_pat)
      edge_mfma<<<8 * SLOTS, 256, 0, stream>>>(phi, plo, psrc, pdst, wfrag, h, agg, flags, meta);
    else
      edge_sorted<<<NEP / 64, 256, 0, stream>>>(eattr, perm, psrc, pdst, edgeW, edgeB, h, agg, flags, meta);
    hipMemsetAsync(bnsum, 0, 128 * sizeof(int), stream);
    mlp_mfma<<<784, 256, 0, stream>>>(h, agg, wpk, b1s, b2s, z2, bnsum, flags, l);
    bn_fin<<<1, 64, 0, stream>>>(bnsum, gam, bet, scsh, flags, l);
    bn_apply<<<3125, 256, 0, stream>>>(z2, scsh, h, agg);
  }
  find_bounds<<<(NN + 255) / 256, 256, 0, stream>>>(batch, bounds, flags);
  pool_final<<<NG, 256, 0, stream>>>(h, bounds, linW, linB, out, flags);
}